// Round 14
// baseline (125.232 us; speedup 1.0000x reference)
//
#include <hip/hip_runtime.h>
#include <hip/hip_bf16.h>

// Shapes (fixed): B=4, V=3, N=256, D=32, H=128
// Outputs (f32, concat flat): node[131072] vl[393216] tl[3072] sp[4096]
//   e[262144] z_rm z_rs z_sm z_ss z_wm z_wsd (262144 each)

#define NEG_INF -1.0e9f
#define EPSC 1e-4f

typedef __attribute__((ext_vector_type(8))) short short8;
typedef __attribute__((ext_vector_type(4))) float f32x4;

__device__ __forceinline__ unsigned short f2bf(float v) {
    unsigned int u = __builtin_bit_cast(unsigned int, v);
    u += 0x7fffu + ((u >> 16) & 1u);
    return (unsigned short)(u >> 16);
}
__device__ __forceinline__ float bf2f(unsigned short h) {
    return __builtin_bit_cast(float, (unsigned int)h << 16);
}
// fast logit: log(p) - log(1-p) via native log (error ~1e-6, e-threshold 2e7)
__device__ __forceinline__ float logit_fast(float p) {
    p = fminf(fmaxf(p, EPSC), 1.0f - EPSC);
    return __logf(p) - __logf(1.0f - p);
}

// ---------- view encoder: input projection (4 rows/block) ----------
__global__ void k_in_proj(const float* __restrict__ x, const float* __restrict__ W,
                          const float* __restrict__ b, float* __restrict__ h) {
    int r0 = blockIdx.x * 4;
    int k = threadIdx.x;
    float bk = b[k];
    float acc[4] = {bk, bk, bk, bk};
#pragma unroll
    for (int d = 0; d < 32; ++d) {
        float w = W[d * 128 + k];
#pragma unroll
        for (int r = 0; r < 4; ++r) acc[r] = fmaf(x[(r0 + r) * 32 + d], w, acc[r]);
    }
#pragma unroll
    for (int r = 0; r < 4; ++r) h[(r0 + r) * 128 + k] = fmaxf(acc[r], 0.f);
}

// ---------- message-passing layer body (4 rows/block, 2/wave) ----------
__device__ __forceinline__ void mp_body(int blk, int t,
        const float* __restrict__ A, const float* __restrict__ hin,
        const float* __restrict__ W, const float* __restrict__ bias,
        float* __restrict__ hout, float (*ms)[128]) {
    int g = blk >> 6;
    int i0 = (blk & 63) * 4;
    int k = t & 127;
    int rh = __builtin_amdgcn_readfirstlane(t >> 7);  // wave-uniform
    const float* Ab = A + (size_t)(g * 256 + i0 + rh * 2) * 256;
    const float* hg = hin + g * 32768;
    float m0 = 0.f, m1 = 0.f;
    for (int j0 = 0; j0 < 256; j0 += 8) {
        float hv[8];
#pragma unroll
        for (int q = 0; q < 8; ++q) hv[q] = hg[(j0 + q) * 128 + k];
#pragma unroll
        for (int q = 0; q < 8; ++q) {
            m0 = fmaf(Ab[j0 + q], hv[q], m0);
            m1 = fmaf(Ab[256 + j0 + q], hv[q], m1);
        }
    }
    ms[rh * 2 + 0][k] = m0;
    ms[rh * 2 + 1][k] = m1;
    __syncthreads();
    float bk = bias[k];
    float a0 = bk, a1 = bk;
    const float* h0 = hg + (i0 + rh * 2) * 128;   // wave-uniform rows -> s_load
    const float* mp0 = ms[rh * 2];
    const float* mp1 = ms[rh * 2 + 1];
    for (int d0 = 0; d0 < 128; d0 += 4) {
        float wa[4], wb[4];
#pragma unroll
        for (int q = 0; q < 4; ++q) {
            wa[q] = W[(d0 + q) * 128 + k];
            wb[q] = W[(128 + d0 + q) * 128 + k];
        }
#pragma unroll
        for (int q = 0; q < 4; ++q) {
            a0 = fmaf(h0[d0 + q], wa[q], a0);
            a1 = fmaf(h0[128 + d0 + q], wa[q], a1);
            a0 = fmaf(mp0[d0 + q], wb[q], a0);
            a1 = fmaf(mp1[d0 + q], wb[q], a1);
        }
    }
    int row = g * 256 + i0 + rh * 2;
    hout[row * 128 + k] = fmaxf(a0, 0.f);
    hout[(row + 1) * 128 + k] = fmaxf(a1, 0.f);
}

__global__ __launch_bounds__(256) void k_mp(const float* __restrict__ A,
        const float* __restrict__ hin, const float* __restrict__ W,
        const float* __restrict__ bias, float* __restrict__ hout) {
    __shared__ float ms[4][128];
    mp_body(blockIdx.x, threadIdx.x, A, hin, W, bias, hout, ms);
}

// ---------- MP layer 0 + evidence stats + hint + Bs prep, merged grid ----------
// blocks 0..767: mp layer; 768..1791: stats; 1792..1935: Bs prep
__global__ __launch_bounds__(256) void k_mp_stats(const float* __restrict__ A,
        const float* __restrict__ hin, const float* __restrict__ W,
        const float* __restrict__ bias, float* __restrict__ hout,
        const float* __restrict__ rel, const float* __restrict__ sup,
        const float* __restrict__ wit, const float* __restrict__ bun,
        unsigned short* __restrict__ ev_bf,
        float* __restrict__ o_rm, float* __restrict__ o_rs,
        float* __restrict__ o_sm, float* __restrict__ o_ss,
        float* __restrict__ o_wm, float* __restrict__ o_wsd,
        const float* __restrict__ eh0w, unsigned short* __restrict__ Bs_g,
        float* __restrict__ hint) {
    __shared__ float ms[4][128];
    int blk = blockIdx.x;
    if (blk < 768) {
        mp_body(blk, threadIdx.x, A, hin, W, bias, hout, ms);
        return;
    }
    blk -= 768;
    if (blk >= 1024) {
        int idx = (blk - 1024) * 256 + threadIdx.x;  // 36864
        int kk = idx >> 12;
        int rem = idx & 4095;
        int n = rem >> 9;
        int l = (rem >> 3) & 63;
        int e = idx & 7;
        int kf = 32 * kk + 8 * (l >> 4) + e;
        int col = 16 * n + (l & 15);
        float v = (kf < 274) ? eh0w[(256 + kf) * 128 + col] : 0.f;
        Bs_g[idx] = f2bf(v);
        return;
    }
    int idx = blk * 256 + threadIdx.x;   // b*65536 + i*256 + j
    int b = idx >> 16;
    int ij = idx & 65535;
    int i = ij >> 8, j = ij & 255;
    int base = b * 3 * 65536 + ij;

    float r0 = rel[base], r1 = rel[base + 65536], r2 = rel[base + 131072];
    float s0 = sup[base], s1 = sup[base + 65536], s2 = sup[base + 131072];
    float w0 = wit[base], w1 = wit[base + 65536], w2 = wit[base + 131072];

    float rm = (r0 + r1 + r2) * (1.f / 3.f);
    float a0 = r0 - rm, a1 = r1 - rm, a2 = r2 - rm;
    float rs = sqrtf((a0 * a0 + a1 * a1 + a2 * a2) * (1.f / 3.f));
    float rmin = fminf(r0, fminf(r1, r2)), rmax = fmaxf(r0, fmaxf(r1, r2));

    float sm = (s0 + s1 + s2) * (1.f / 3.f);
    a0 = s0 - sm; a1 = s1 - sm; a2 = s2 - sm;
    float ss = sqrtf((a0 * a0 + a1 * a1 + a2 * a2) * (1.f / 3.f));
    float smin = fminf(s0, fminf(s1, s2)), smax = fmaxf(s0, fmaxf(s1, s2));

    float wm = (w0 + w1 + w2) * (1.f / 3.f);
    a0 = w0 - wm; a1 = w1 - wm; a2 = w2 - wm;
    float wsd = sqrtf((a0 * a0 + a1 * a1 + a2 * a2) * (1.f / 3.f));

    // precompute the logit hint here (hidden under mp0); k_final just adds it
    hint[idx] = logit_fast(0.5f * (rm + sm));

    union { unsigned short us[32]; uint4 q[4]; } pk;
    pk.us[0] = f2bf(rm);  pk.us[1] = f2bf(rs);
    pk.us[2] = f2bf(rmin); pk.us[3] = f2bf(rmax);
    pk.us[4] = f2bf(sm);  pk.us[5] = f2bf(ss);
    pk.us[6] = f2bf(smin); pk.us[7] = f2bf(smax);
    pk.us[8] = f2bf(wm);  pk.us[9] = f2bf(wsd);
    int bb = base * 4;
    float4 bv0 = *(const float4*)&bun[bb];
    float4 bv1 = *(const float4*)&bun[bb + 262144];
    float4 bv2 = *(const float4*)&bun[bb + 524288];
    const float* p0 = (const float*)&bv0;
    const float* p1 = (const float*)&bv1;
    const float* p2 = (const float*)&bv2;
#pragma unroll
    for (int c = 0; c < 4; ++c) {
        float b0 = p0[c], b1 = p1[c], b2 = p2[c];
        float bm = (b0 + b1 + b2) * (1.f / 3.f);
        float d0 = b0 - bm, d1 = b1 - bm, d2 = b2 - bm;
        pk.us[10 + c] = f2bf(bm);
        pk.us[14 + c] = f2bf(sqrtf((d0 * d0 + d1 * d1 + d2 * d2) * (1.f / 3.f)));
    }
#pragma unroll
    for (int c = 18; c < 32; ++c) pk.us[c] = 0;
    uint4* dst = (uint4*)&ev_bf[(size_t)idx * 32];
    dst[0] = pk.q[0]; dst[1] = pk.q[1]; dst[2] = pk.q[2]; dst[3] = pk.q[3];

    bool diag = (i == j);
    o_rm[idx] = diag ? 0.f : rm;
    o_rs[idx] = diag ? 0.f : rs;
    o_sm[idx] = diag ? 0.f : sm;
    o_ss[idx] = diag ? 0.f : ss;
    o_wm[idx] = diag ? 0.f : wm;
    o_wsd[idx] = diag ? 0.f : wsd;
}

// ---------- fused node + heads + Ti/Tj: 2 rows per block, 256 threads ----------
__global__ __launch_bounds__(256) void k_fuse(const float* __restrict__ vl,
        const float* __restrict__ nf0w, const float* __restrict__ nf0b,
        const float* __restrict__ nf1w, const float* __restrict__ nf1b,
        const float* __restrict__ th0w, const float* __restrict__ th0b,
        const float* __restrict__ th1w, const float* __restrict__ th1b,
        const float* __restrict__ sh0w, const float* __restrict__ sh0b,
        const float* __restrict__ sh1w, const float* __restrict__ sh1b,
        const float* __restrict__ eh0w, const float* __restrict__ eh0b,
        float* __restrict__ node_out, unsigned short* __restrict__ nodeS_g,
        float* __restrict__ tl, float* __restrict__ sp,
        float* __restrict__ Ti, unsigned short* __restrict__ Tjt) {
    int bn0 = blockIdx.x * 2;
    int b = bn0 >> 8;               // rows never cross a b boundary (bn0 even)
    int t = threadIdx.x;
    int k = t & 127;
    int r = __builtin_amdgcn_readfirstlane(t >> 7);   // row 0/1, wave-uniform
    int bn = bn0 + r;
    int n = bn & 255;
    __shared__ float fused[2][256];
    __shared__ float g[2][128];
    __shared__ float nd[2][128];
    __shared__ float red7[2][7][128];

    // stage 1: mean/std over views
    {
        float v0 = vl[((b * 3 + 0) * 256 + n) * 128 + k];
        float v1 = vl[((b * 3 + 1) * 256 + n) * 128 + k];
        float v2 = vl[((b * 3 + 2) * 256 + n) * 128 + k];
        float mean = (v0 + v1 + v2) * (1.f / 3.f);
        float d0_ = v0 - mean, d1_ = v1 - mean, d2_ = v2 - mean;
        fused[r][k] = mean;
        fused[r][128 + k] = sqrtf((d0_ * d0_ + d1_ * d1_ + d2_ * d2_) * (1.f / 3.f));
    }
    __syncthreads();

    // stage 2: g = relu(fused @ nf0w + b), 8-deep batched loads
    {
        float a = nf0b[k];
        const float* fr = fused[r];
        for (int d0 = 0; d0 < 256; d0 += 8) {
            float wv[8];
#pragma unroll
            for (int q = 0; q < 8; ++q) wv[q] = nf0w[(d0 + q) * 128 + k];
#pragma unroll
            for (int q = 0; q < 8; ++q) a = fmaf(fr[d0 + q], wv[q], a);
        }
        g[r][k] = fmaxf(a, 0.f);
    }
    __syncthreads();

    // stage 3: node = g @ nf1w + b
    {
        float v = nf1b[k];
        const float* gr = g[r];
        for (int d0 = 0; d0 < 128; d0 += 8) {
            float wv[8];
#pragma unroll
            for (int q = 0; q < 8; ++q) wv[q] = nf1w[(d0 + q) * 128 + k];
#pragma unroll
            for (int q = 0; q < 8; ++q) v = fmaf(gr[d0 + q], wv[q], v);
        }
        node_out[bn * 128 + k] = v;
        nodeS_g[b * 32768 + (n >> 4) * 2048 + (k >> 3) * 128 + (n & 15) * 8 + (k & 7)] =
            f2bf(v);
        nd[r][k] = v;
    }
    __syncthreads();

    // stage 4: four weight streams, 16 loads in flight
    float at = th0b[k], as = sh0b[k], ai = eh0b[k], aj = 0.f;
    {
        const float* nr = nd[r];
        for (int d0 = 0; d0 < 128; d0 += 4) {
            float wt[4], wsv[4], wi[4], wj[4];
#pragma unroll
            for (int q = 0; q < 4; ++q) {
                wt[q] = th0w[(d0 + q) * 128 + k];
                wsv[q] = sh0w[(d0 + q) * 128 + k];
                wi[q] = eh0w[(d0 + q) * 128 + k];
                wj[q] = eh0w[(128 + d0 + q) * 128 + k];
            }
#pragma unroll
            for (int q = 0; q < 4; ++q) {
                float nv = nr[d0 + q];
                at = fmaf(nv, wt[q], at);
                as = fmaf(nv, wsv[q], as);
                ai = fmaf(nv, wi[q], ai);
                aj = fmaf(nv, wj[q], aj);
            }
        }
    }
    Ti[bn * 128 + k] = ai;
    Tjt[((size_t)(b * 128 + k)) * 256 + n] = f2bf(aj);
    float gtk = fmaxf(at, 0.f), gsk = fmaxf(as, 0.f);

    // stage 5: head tails — write all 7 products, ONE barrier, sync-free reduce
#pragma unroll
    for (int o = 0; o < 7; ++o) {
        bool isT = o < 3;
        float wv = isT ? th1w[k * 3 + o] : sh1w[k * 4 + (o - 3)];
        red7[r][o][k] = (isT ? gtk : gsk) * wv;
    }
    __syncthreads();
    if (t < 128) {
        int rr = t >> 6;        // row handled by this half
        int l = t & 63;
#pragma unroll
        for (int o = 0; o < 7; ++o) {
            float s = red7[rr][o][l] + red7[rr][o][l + 64];
#pragma unroll
            for (int mk = 32; mk >= 1; mk >>= 1) s += __shfl_xor(s, mk);
            if (l == 0) {
                int bno = bn0 + rr;
                if (o < 3) tl[bno * 3 + o] = s + th1b[o];
                else sp[bno * 4 + (o - 3)] = s + sh1b[o - 3];
            }
        }
    }
}

// ---------- edge head: MFMA bf16 — frozen dataflow; Bs from GLOBAL (L2) ----------
// LDS = node panel only (64 KB) -> 2 blocks/CU -> 4 waves/SIMD (2x occupancy)
// block = (b, i-pair): 8 waves, wave w -> i = i0+(w>>2), j-chunk = (w&3)*64
// A[j][K=288]: [ |hi-hj| 128 | hi*hj 128 | ev 18 | pad 14 ], B = staged weights
__global__ __launch_bounds__(512, 2) void k_edge(
        const unsigned short* __restrict__ nodeS_g,
        const unsigned short* __restrict__ Bs_g,
        const unsigned short* __restrict__ ev_bf,
        const unsigned short* __restrict__ Tjt,
        const float* __restrict__ Ti_g, const float* __restrict__ eh1w,
        float* __restrict__ ep) {
    __shared__ short lds[32768];   // node panel only: 65536 B
    int tid = threadIdx.x;
    int blk = blockIdx.x;
    int b = blk >> 7;
    int i0 = (blk & 127) << 1;

    {   // stage node panel (source layout identical to LDS layout)
        const short8* srcN = (const short8*)(nodeS_g + (size_t)b * 32768);
        short8* dstN = (short8*)lds;
        for (int t = tid; t < 4096; t += 512) dstN[t] = srcN[t];
    }
    __syncthreads();

    int w = tid >> 6, lane = tid & 63;
    int i = i0 + (w >> 2);
    int j0 = (w & 3) << 6;
    int g = lane >> 4, l15 = lane & 15;
    int bi = b * 256 + i;

    float ti[8], w1r[8];
#pragma unroll
    for (int n = 0; n < 8; ++n) {
        ti[n] = Ti_g[bi * 128 + 16 * n + l15];
        w1r[n] = eh1w[16 * n + l15];
    }

    f32x4 acc[4][8];
#pragma unroll
    for (int m = 0; m < 4; ++m)
#pragma unroll
        for (int n = 0; n < 8; ++n) acc[m][n] = (f32x4){0.f, 0.f, 0.f, 0.f};

    int jt0 = j0 >> 4;
    int jti = i >> 4;
    const short8* Bsv = (const short8*)Bs_g;   // [kk*8+n][lane] 16B frags, L2-hot

    for (int kk = 0; kk < 8; ++kk) {
        int kkm = kk & 3;
        bool isPr = kk >= 4;
        short8 bfr[8];
#pragma unroll
        for (int n = 0; n < 8; ++n)
            bfr[n] = Bsv[(kk * 8 + n) * 64 + lane];
        short8 hi8 = *(const short8*)&lds[jti * 2048 + kkm * 512 + g * 128 + (i & 15) * 8];
        float hif[8];
#pragma unroll
        for (int e = 0; e < 8; ++e) hif[e] = bf2f((unsigned short)hi8[e]);
#pragma unroll
        for (int m = 0; m < 4; ++m) {
            short8 hj8 = *(const short8*)&lds[(jt0 + m) * 2048 + kkm * 512 + lane * 8];
            short8 a;
#pragma unroll
            for (int e = 0; e < 8; ++e) {
                float hj = bf2f((unsigned short)hj8[e]);
                float v = isPr ? hif[e] * hj : fabsf(hif[e] - hj);
                // truncating bf16 pack: 1 op vs 3-op RTNE (error <= 1 ulp bf16)
                a[e] = (short)(__builtin_bit_cast(unsigned int, v) >> 16);
            }
#pragma unroll
            for (int n = 0; n < 8; ++n)
                acc[m][n] = __builtin_amdgcn_mfma_f32_16x16x32_bf16(a, bfr[n], acc[m][n], 0, 0, 0);
        }
    }
    {   // kk = 8: ev features straight from ev_bf (already bf16, padded to 32)
        short8 bfr[8];
#pragma unroll
        for (int n = 0; n < 8; ++n)
            bfr[n] = Bsv[(64 + n) * 64 + lane];
#pragma unroll
        for (int m = 0; m < 4; ++m) {
            int j = j0 + 16 * m + l15;
            short8 a = *(const short8*)&ev_bf[((size_t)(bi * 256 + j)) * 32 + 8 * g];
#pragma unroll
            for (int n = 0; n < 8; ++n)
                acc[m][n] = __builtin_amdgcn_mfma_f32_16x16x32_bf16(a, bfr[n], acc[m][n], 0, 0, 0);
        }
    }
    // epilogue: + Ti[k] + Tj[j][k], relu, * w1[k], reduce over k, write e_pre
#pragma unroll
    for (int m = 0; m < 4; ++m) {
        int jb = j0 + 16 * m + 4 * g;
        float s0 = 0.f, s1 = 0.f, s2 = 0.f, s3 = 0.f;
#pragma unroll
        for (int n = 0; n < 8; ++n) {
            int kidx = 16 * n + l15;
            uint2 tj = *(const uint2*)&Tjt[((size_t)(b * 128 + kidx)) * 256 + jb];
            float tb = ti[n];
            float h0 = acc[m][n][0] + tb + bf2f((unsigned short)(tj.x & 0xffff));
            float h1 = acc[m][n][1] + tb + bf2f((unsigned short)(tj.x >> 16));
            float h2 = acc[m][n][2] + tb + bf2f((unsigned short)(tj.y & 0xffff));
            float h3 = acc[m][n][3] + tb + bf2f((unsigned short)(tj.y >> 16));
            float wk = w1r[n];
            s0 += fmaxf(h0, 0.f) * wk;
            s1 += fmaxf(h1, 0.f) * wk;
            s2 += fmaxf(h2, 0.f) * wk;
            s3 += fmaxf(h3, 0.f) * wk;
        }
#pragma unroll
        for (int mk = 1; mk < 16; mk <<= 1) {
            s0 += __shfl_xor(s0, mk);
            s1 += __shfl_xor(s1, mk);
            s2 += __shfl_xor(s2, mk);
            s3 += __shfl_xor(s3, mk);
        }
        if (l15 == 0)
            *(float4*)&ep[(size_t)bi * 256 + jb] = make_float4(s0, s1, s2, s3);
    }
}

// ---------- final e: pure BW — ep/hint + transposed tiles ----------
__global__ __launch_bounds__(256) void k_final(const float* __restrict__ ep,
        const float* __restrict__ hint, const float* __restrict__ eh1b,
        float* __restrict__ e_out) {
    int blk = blockIdx.x;
    int b = blk >> 6;
    int ti = (blk >> 3) & 7, tj = blk & 7;
    int i0 = ti * 32, j0 = tj * 32;
    int t = threadIdx.x;
    int c = t & 31;
    int r4 = (t >> 5) * 4;
    __shared__ float epT[32][33], hT[32][33];
#pragma unroll
    for (int q = 0; q < 4; ++q) {
        int r = r4 + q;
        int src = ((b << 8) + j0 + r) * 256 + i0 + c;
        epT[c][r] = ep[src];
        hT[c][r] = hint[src];
    }
    __syncthreads();
    float bias2 = 2.0f * eh1b[0];
#pragma unroll
    for (int q = 0; q < 4; ++q) {
        int a = r4 + q;
        int i = i0 + a, j = j0 + c;
        int idx = ((b << 8) + i) * 256 + j;
        float s = ep[idx] + hint[idx] + epT[a][c] + hT[a][c] + bias2;
        e_out[idx] = (i == j) ? NEG_INF : 0.5f * s;
    }
}

extern "C" void kernel_launch(void* const* d_in, const int* in_sizes, int n_in,
                              void* d_out, int out_size, void* d_ws, size_t ws_size,
                              hipStream_t stream) {
    const float* slots = (const float*)d_in[0];
    const float* rel   = (const float*)d_in[1];
    const float* sup   = (const float*)d_in[2];
    const float* wit   = (const float*)d_in[3];
    const float* bun   = (const float*)d_in[4];
    const float* ve_in_w = (const float*)d_in[5];
    const float* ve_in_b = (const float*)d_in[6];
    const float* ve_w[3] = {(const float*)d_in[7], (const float*)d_in[9], (const float*)d_in[11]};
    const float* ve_b[3] = {(const float*)d_in[8], (const float*)d_in[10], (const float*)d_in[12]};
    const float* nf0w = (const float*)d_in[13];
    const float* nf0b = (const float*)d_in[14];
    const float* nf1w = (const float*)d_in[15];
    const float* nf1b = (const float*)d_in[16];
    const float* th0w = (const float*)d_in[17];
    const float* th0b = (const float*)d_in[18];
    const float* th1w = (const float*)d_in[19];
    const float* th1b = (const float*)d_in[20];
    const float* sh0w = (const float*)d_in[21];
    const float* sh0b = (const float*)d_in[22];
    const float* sh1w = (const float*)d_in[23];
    const float* sh1b = (const float*)d_in[24];
    const float* eh0w = (const float*)d_in[25];
    const float* eh0b = (const float*)d_in[26];
    const float* eh1w = (const float*)d_in[27];
    const float* eh1b = (const float*)d_in[28];

    float* out = (float*)d_out;
    float* o_node = out;
    float* o_vl   = out + 131072;
    float* o_tl   = out + 524288;
    float* o_sp   = out + 527360;
    float* o_e    = out + 531456;
    float* o_rm   = out + 793600;
    float* o_rs   = out + 1055744;
    float* o_sm   = out + 1317888;
    float* o_ss   = out + 1580032;
    float* o_wm   = out + 1842176;
    float* o_wsd  = out + 2104320;

    float* ws  = (float*)d_ws;
    float* h_a = ws;                                   // 393216
    float* h_b = ws + 393216;                          // 393216
    float* Ti  = ws + 786432;                          // 131072
    float* ep  = ws + 917504;                          // 262144
    unsigned short* ev_bf  = (unsigned short*)(ws + 1179648);  // 8388608 hw
    unsigned short* Tjt    = (unsigned short*)(ws + 5373952);  // 131072 hw
    unsigned short* nodeSg = (unsigned short*)(ws + 5439488);  // 131072 hw
    unsigned short* Bs_g   = (unsigned short*)(ws + 5505024);  // 36864 hw
    float* hint = ws + 5523456;                        // 262144 (ends 5785600 = 23.1 MB)

    k_in_proj<<<768, 128, 0, stream>>>(slots, ve_in_w, ve_in_b, h_a);
    // MP layer 0 merged with independent stats/hint/prep work (fills idle CUs)
    k_mp_stats<<<1936, 256, 0, stream>>>(rel, h_a, ve_w[0], ve_b[0], h_b,
                                         rel, sup, wit, bun, ev_bf,
                                         o_rm, o_rs, o_sm, o_ss, o_wm, o_wsd,
                                         eh0w, Bs_g, hint);
    k_mp<<<768, 256, 0, stream>>>(rel, h_b, ve_w[1], ve_b[1], h_a);
    k_mp<<<768, 256, 0, stream>>>(rel, h_a, ve_w[2], ve_b[2], o_vl);

    k_fuse<<<512, 256, 0, stream>>>(o_vl, nf0w, nf0b, nf1w, nf1b,
                                    th0w, th0b, th1w, th1b,
                                    sh0w, sh0b, sh1w, sh1b,
                                    eh0w, eh0b,
                                    o_node, nodeSg, o_tl, o_sp, Ti, Tjt);
    k_edge<<<512, 512, 0, stream>>>(nodeSg, Bs_g, ev_bf, Tjt, Ti, eh1w, ep);
    k_final<<<256, 256, 0, stream>>>(ep, hint, eh1b, o_e);
}

// Round 15
// 121.386 us; speedup vs baseline: 1.0317x; 1.0317x over previous
//
#include <hip/hip_runtime.h>
#include <hip/hip_bf16.h>

// Shapes (fixed): B=4, V=3, N=256, D=32, H=128
// Outputs (f32, concat flat): node[131072] vl[393216] tl[3072] sp[4096]
//   e[262144] z_rm z_rs z_sm z_ss z_wm z_wsd (262144 each)

#define NEG_INF -1.0e9f
#define EPSC 1e-4f

typedef __attribute__((ext_vector_type(8))) short short8;
typedef __attribute__((ext_vector_type(4))) float f32x4;

__device__ __forceinline__ unsigned short f2bf(float v) {
    unsigned int u = __builtin_bit_cast(unsigned int, v);
    u += 0x7fffu + ((u >> 16) & 1u);
    return (unsigned short)(u >> 16);
}
__device__ __forceinline__ float bf2f(unsigned short h) {
    return __builtin_bit_cast(float, (unsigned int)h << 16);
}
// fast logit: log(p) - log(1-p) via native log (error ~1e-6, e-threshold 2e7)
__device__ __forceinline__ float logit_fast(float p) {
    p = fminf(fmaxf(p, EPSC), 1.0f - EPSC);
    return __logf(p) - __logf(1.0f - p);
}

// ---------- view encoder: input projection (4 rows/block) ----------
__global__ void k_in_proj(const float* __restrict__ x, const float* __restrict__ W,
                          const float* __restrict__ b, float* __restrict__ h) {
    int r0 = blockIdx.x * 4;
    int k = threadIdx.x;
    float bk = b[k];
    float acc[4] = {bk, bk, bk, bk};
#pragma unroll
    for (int d = 0; d < 32; ++d) {
        float w = W[d * 128 + k];
#pragma unroll
        for (int r = 0; r < 4; ++r) acc[r] = fmaf(x[(r0 + r) * 32 + d], w, acc[r]);
    }
#pragma unroll
    for (int r = 0; r < 4; ++r) h[(r0 + r) * 128 + k] = fmaxf(acc[r], 0.f);
}

// ---------- message-passing layer body (4 rows/block, 2/wave) ----------
// Accumulator chains split 4-way (msg) / 2-way (layer) to cut dep latency.
__device__ __forceinline__ void mp_body(int blk, int t,
        const float* __restrict__ A, const float* __restrict__ hin,
        const float* __restrict__ W, const float* __restrict__ bias,
        float* __restrict__ hout, float (*ms)[128]) {
    int g = blk >> 6;
    int i0 = (blk & 63) * 4;
    int k = t & 127;
    int rh = __builtin_amdgcn_readfirstlane(t >> 7);  // wave-uniform
    const float* Ab = A + (size_t)(g * 256 + i0 + rh * 2) * 256;
    const float* hg = hin + g * 32768;
    float m0p[4] = {0.f, 0.f, 0.f, 0.f};
    float m1p[4] = {0.f, 0.f, 0.f, 0.f};
    for (int j0 = 0; j0 < 256; j0 += 8) {
        float hv[8];
#pragma unroll
        for (int q = 0; q < 8; ++q) hv[q] = hg[(j0 + q) * 128 + k];
#pragma unroll
        for (int q = 0; q < 8; ++q) {
            m0p[q & 3] = fmaf(Ab[j0 + q], hv[q], m0p[q & 3]);
            m1p[q & 3] = fmaf(Ab[256 + j0 + q], hv[q], m1p[q & 3]);
        }
    }
    float m0 = (m0p[0] + m0p[1]) + (m0p[2] + m0p[3]);
    float m1 = (m1p[0] + m1p[1]) + (m1p[2] + m1p[3]);
    ms[rh * 2 + 0][k] = m0;
    ms[rh * 2 + 1][k] = m1;
    __syncthreads();
    float bk = bias[k];
    const float* h0 = hg + (i0 + rh * 2) * 128;   // wave-uniform rows -> s_load
    const float* mp0 = ms[rh * 2];
    const float* mp1 = ms[rh * 2 + 1];
    // independent h-part and m-part accumulators (2 chains each of 128)
    float a0h = bk, a0m = 0.f, a1h = bk, a1m = 0.f;
    for (int d0 = 0; d0 < 128; d0 += 4) {
        float wa[4], wb[4];
#pragma unroll
        for (int q = 0; q < 4; ++q) {
            wa[q] = W[(d0 + q) * 128 + k];
            wb[q] = W[(128 + d0 + q) * 128 + k];
        }
#pragma unroll
        for (int q = 0; q < 4; ++q) {
            a0h = fmaf(h0[d0 + q], wa[q], a0h);
            a1h = fmaf(h0[128 + d0 + q], wa[q], a1h);
            a0m = fmaf(mp0[d0 + q], wb[q], a0m);
            a1m = fmaf(mp1[d0 + q], wb[q], a1m);
        }
    }
    int row = g * 256 + i0 + rh * 2;
    hout[row * 128 + k] = fmaxf(a0h + a0m, 0.f);
    hout[(row + 1) * 128 + k] = fmaxf(a1h + a1m, 0.f);
}

__global__ __launch_bounds__(256) void k_mp(const float* __restrict__ A,
        const float* __restrict__ hin, const float* __restrict__ W,
        const float* __restrict__ bias, float* __restrict__ hout) {
    __shared__ float ms[4][128];
    mp_body(blockIdx.x, threadIdx.x, A, hin, W, bias, hout, ms);
}

// ---------- MP layer 0 + evidence stats + hint + Bs prep, merged grid ----------
// blocks 0..767: mp layer; 768..1791: stats; 1792..1935: Bs prep
__global__ __launch_bounds__(256) void k_mp_stats(const float* __restrict__ A,
        const float* __restrict__ hin, const float* __restrict__ W,
        const float* __restrict__ bias, float* __restrict__ hout,
        const float* __restrict__ rel, const float* __restrict__ sup,
        const float* __restrict__ wit, const float* __restrict__ bun,
        unsigned short* __restrict__ ev_bf,
        float* __restrict__ o_rm, float* __restrict__ o_rs,
        float* __restrict__ o_sm, float* __restrict__ o_ss,
        float* __restrict__ o_wm, float* __restrict__ o_wsd,
        const float* __restrict__ eh0w, unsigned short* __restrict__ Bs_g,
        float* __restrict__ hint) {
    __shared__ float ms[4][128];
    int blk = blockIdx.x;
    if (blk < 768) {
        mp_body(blk, threadIdx.x, A, hin, W, bias, hout, ms);
        return;
    }
    blk -= 768;
    if (blk >= 1024) {
        int idx = (blk - 1024) * 256 + threadIdx.x;  // 36864
        int kk = idx >> 12;
        int rem = idx & 4095;
        int n = rem >> 9;
        int l = (rem >> 3) & 63;
        int e = idx & 7;
        int kf = 32 * kk + 8 * (l >> 4) + e;
        int col = 16 * n + (l & 15);
        float v = (kf < 274) ? eh0w[(256 + kf) * 128 + col] : 0.f;
        Bs_g[idx] = f2bf(v);
        return;
    }
    int idx = blk * 256 + threadIdx.x;   // b*65536 + i*256 + j
    int b = idx >> 16;
    int ij = idx & 65535;
    int i = ij >> 8, j = ij & 255;
    int base = b * 3 * 65536 + ij;

    float r0 = rel[base], r1 = rel[base + 65536], r2 = rel[base + 131072];
    float s0 = sup[base], s1 = sup[base + 65536], s2 = sup[base + 131072];
    float w0 = wit[base], w1 = wit[base + 65536], w2 = wit[base + 131072];

    float rm = (r0 + r1 + r2) * (1.f / 3.f);
    float a0 = r0 - rm, a1 = r1 - rm, a2 = r2 - rm;
    float rs = sqrtf((a0 * a0 + a1 * a1 + a2 * a2) * (1.f / 3.f));
    float rmin = fminf(r0, fminf(r1, r2)), rmax = fmaxf(r0, fmaxf(r1, r2));

    float sm = (s0 + s1 + s2) * (1.f / 3.f);
    a0 = s0 - sm; a1 = s1 - sm; a2 = s2 - sm;
    float ss = sqrtf((a0 * a0 + a1 * a1 + a2 * a2) * (1.f / 3.f));
    float smin = fminf(s0, fminf(s1, s2)), smax = fmaxf(s0, fmaxf(s1, s2));

    float wm = (w0 + w1 + w2) * (1.f / 3.f);
    a0 = w0 - wm; a1 = w1 - wm; a2 = w2 - wm;
    float wsd = sqrtf((a0 * a0 + a1 * a1 + a2 * a2) * (1.f / 3.f));

    // precompute the logit hint here (hidden under mp0); k_final just adds it
    hint[idx] = logit_fast(0.5f * (rm + sm));

    union { unsigned short us[32]; uint4 q[4]; } pk;
    pk.us[0] = f2bf(rm);  pk.us[1] = f2bf(rs);
    pk.us[2] = f2bf(rmin); pk.us[3] = f2bf(rmax);
    pk.us[4] = f2bf(sm);  pk.us[5] = f2bf(ss);
    pk.us[6] = f2bf(smin); pk.us[7] = f2bf(smax);
    pk.us[8] = f2bf(wm);  pk.us[9] = f2bf(wsd);
    int bb = base * 4;
    float4 bv0 = *(const float4*)&bun[bb];
    float4 bv1 = *(const float4*)&bun[bb + 262144];
    float4 bv2 = *(const float4*)&bun[bb + 524288];
    const float* p0 = (const float*)&bv0;
    const float* p1 = (const float*)&bv1;
    const float* p2 = (const float*)&bv2;
#pragma unroll
    for (int c = 0; c < 4; ++c) {
        float b0 = p0[c], b1 = p1[c], b2 = p2[c];
        float bm = (b0 + b1 + b2) * (1.f / 3.f);
        float d0 = b0 - bm, d1 = b1 - bm, d2 = b2 - bm;
        pk.us[10 + c] = f2bf(bm);
        pk.us[14 + c] = f2bf(sqrtf((d0 * d0 + d1 * d1 + d2 * d2) * (1.f / 3.f)));
    }
#pragma unroll
    for (int c = 18; c < 32; ++c) pk.us[c] = 0;
    uint4* dst = (uint4*)&ev_bf[(size_t)idx * 32];
    dst[0] = pk.q[0]; dst[1] = pk.q[1]; dst[2] = pk.q[2]; dst[3] = pk.q[3];

    bool diag = (i == j);
    o_rm[idx] = diag ? 0.f : rm;
    o_rs[idx] = diag ? 0.f : rs;
    o_sm[idx] = diag ? 0.f : sm;
    o_ss[idx] = diag ? 0.f : ss;
    o_wm[idx] = diag ? 0.f : wm;
    o_wsd[idx] = diag ? 0.f : wsd;
}

// ---------- fused node + heads + Ti/Tj: 2 rows per block, 256 threads ----------
__global__ __launch_bounds__(256) void k_fuse(const float* __restrict__ vl,
        const float* __restrict__ nf0w, const float* __restrict__ nf0b,
        const float* __restrict__ nf1w, const float* __restrict__ nf1b,
        const float* __restrict__ th0w, const float* __restrict__ th0b,
        const float* __restrict__ th1w, const float* __restrict__ th1b,
        const float* __restrict__ sh0w, const float* __restrict__ sh0b,
        const float* __restrict__ sh1w, const float* __restrict__ sh1b,
        const float* __restrict__ eh0w, const float* __restrict__ eh0b,
        float* __restrict__ node_out, unsigned short* __restrict__ nodeS_g,
        float* __restrict__ tl, float* __restrict__ sp,
        float* __restrict__ Ti, unsigned short* __restrict__ Tjt) {
    int bn0 = blockIdx.x * 2;
    int b = bn0 >> 8;               // rows never cross a b boundary (bn0 even)
    int t = threadIdx.x;
    int k = t & 127;
    int r = __builtin_amdgcn_readfirstlane(t >> 7);   // row 0/1, wave-uniform
    int bn = bn0 + r;
    int n = bn & 255;
    __shared__ float fused[2][256];
    __shared__ float g[2][128];
    __shared__ float nd[2][128];
    __shared__ float red7[2][7][128];

    // stage 1: mean/std over views
    {
        float v0 = vl[((b * 3 + 0) * 256 + n) * 128 + k];
        float v1 = vl[((b * 3 + 1) * 256 + n) * 128 + k];
        float v2 = vl[((b * 3 + 2) * 256 + n) * 128 + k];
        float mean = (v0 + v1 + v2) * (1.f / 3.f);
        float d0_ = v0 - mean, d1_ = v1 - mean, d2_ = v2 - mean;
        fused[r][k] = mean;
        fused[r][128 + k] = sqrtf((d0_ * d0_ + d1_ * d1_ + d2_ * d2_) * (1.f / 3.f));
    }
    __syncthreads();

    // stage 2: g = relu(fused @ nf0w + b), 2-way split chains
    {
        float ap0 = nf0b[k], ap1 = 0.f;
        const float* fr = fused[r];
        for (int d0 = 0; d0 < 256; d0 += 8) {
            float wv[8];
#pragma unroll
            for (int q = 0; q < 8; ++q) wv[q] = nf0w[(d0 + q) * 128 + k];
#pragma unroll
            for (int q = 0; q < 8; ++q) {
                if (q & 1) ap1 = fmaf(fr[d0 + q], wv[q], ap1);
                else       ap0 = fmaf(fr[d0 + q], wv[q], ap0);
            }
        }
        g[r][k] = fmaxf(ap0 + ap1, 0.f);
    }
    __syncthreads();

    // stage 3: node = g @ nf1w + b, 2-way split chains
    {
        float vp0 = nf1b[k], vp1 = 0.f;
        const float* gr = g[r];
        for (int d0 = 0; d0 < 128; d0 += 8) {
            float wv[8];
#pragma unroll
            for (int q = 0; q < 8; ++q) wv[q] = nf1w[(d0 + q) * 128 + k];
#pragma unroll
            for (int q = 0; q < 8; ++q) {
                if (q & 1) vp1 = fmaf(gr[d0 + q], wv[q], vp1);
                else       vp0 = fmaf(gr[d0 + q], wv[q], vp0);
            }
        }
        float v = vp0 + vp1;
        node_out[bn * 128 + k] = v;
        nodeS_g[b * 32768 + (n >> 4) * 2048 + (k >> 3) * 128 + (n & 15) * 8 + (k & 7)] =
            f2bf(v);
        nd[r][k] = v;
    }
    __syncthreads();

    // stage 4: four weight streams (4 independent chains), 16 loads in flight
    float at = th0b[k], as = sh0b[k], ai = eh0b[k], aj = 0.f;
    {
        const float* nr = nd[r];
        for (int d0 = 0; d0 < 128; d0 += 4) {
            float wt[4], wsv[4], wi[4], wj[4];
#pragma unroll
            for (int q = 0; q < 4; ++q) {
                wt[q] = th0w[(d0 + q) * 128 + k];
                wsv[q] = sh0w[(d0 + q) * 128 + k];
                wi[q] = eh0w[(d0 + q) * 128 + k];
                wj[q] = eh0w[(128 + d0 + q) * 128 + k];
            }
#pragma unroll
            for (int q = 0; q < 4; ++q) {
                float nv = nr[d0 + q];
                at = fmaf(nv, wt[q], at);
                as = fmaf(nv, wsv[q], as);
                ai = fmaf(nv, wi[q], ai);
                aj = fmaf(nv, wj[q], aj);
            }
        }
    }
    Ti[bn * 128 + k] = ai;
    Tjt[((size_t)(b * 128 + k)) * 256 + n] = f2bf(aj);
    float gtk = fmaxf(at, 0.f), gsk = fmaxf(as, 0.f);

    // stage 5: head tails — write all 7 products, ONE barrier, sync-free reduce
#pragma unroll
    for (int o = 0; o < 7; ++o) {
        bool isT = o < 3;
        float wv = isT ? th1w[k * 3 + o] : sh1w[k * 4 + (o - 3)];
        red7[r][o][k] = (isT ? gtk : gsk) * wv;
    }
    __syncthreads();
    if (t < 128) {
        int rr = t >> 6;        // row handled by this half
        int l = t & 63;
#pragma unroll
        for (int o = 0; o < 7; ++o) {
            float s = red7[rr][o][l] + red7[rr][o][l + 64];
#pragma unroll
            for (int mk = 32; mk >= 1; mk >>= 1) s += __shfl_xor(s, mk);
            if (l == 0) {
                int bno = bn0 + rr;
                if (o < 3) tl[bno * 3 + o] = s + th1b[o];
                else sp[bno * 4 + (o - 3)] = s + sh1b[o - 3];
            }
        }
    }
}

// ---------- edge head: MFMA bf16 — FROZEN round-13 text (45.4us, no spill) ----------
// block = (b, i-pair): 8 waves, wave w -> i = i0+(w>>2), j-chunk = (w&3)*64
// A[j][K=288]: [ |hi-hj| 128 | hi*hj 128 | ev 18 | pad 14 ], B = staged weights
__global__ __launch_bounds__(512, 2) void k_edge(
        const unsigned short* __restrict__ nodeS_g,
        const unsigned short* __restrict__ Bs_g,
        const unsigned short* __restrict__ ev_bf,
        const unsigned short* __restrict__ Tjt,
        const float* __restrict__ Ti_g, const float* __restrict__ eh1w,
        float* __restrict__ ep) {
    __shared__ short lds[69632];   // node panel 32768 hw + Bs 36864 hw = 139264 B
    int tid = threadIdx.x;
    int blk = blockIdx.x;
    int b = blk >> 7;
    int i0 = (blk & 127) << 1;

    {   // stage: both source layouts are identical to LDS layouts (linear copy)
        const short8* srcN = (const short8*)(nodeS_g + (size_t)b * 32768);
        short8* dstN = (short8*)lds;
        for (int t = tid; t < 4096; t += 512) dstN[t] = srcN[t];
        const short8* srcB = (const short8*)Bs_g;
        short8* dstB = (short8*)(lds + 32768);
        for (int t = tid; t < 4608; t += 512) dstB[t] = srcB[t];
    }
    __syncthreads();

    int w = tid >> 6, lane = tid & 63;
    int i = i0 + (w >> 2);
    int j0 = (w & 3) << 6;
    int g = lane >> 4, l15 = lane & 15;
    int bi = b * 256 + i;

    float ti[8], w1r[8];
#pragma unroll
    for (int n = 0; n < 8; ++n) {
        ti[n] = Ti_g[bi * 128 + 16 * n + l15];
        w1r[n] = eh1w[16 * n + l15];
    }

    f32x4 acc[4][8];
#pragma unroll
    for (int m = 0; m < 4; ++m)
#pragma unroll
        for (int n = 0; n < 8; ++n) acc[m][n] = (f32x4){0.f, 0.f, 0.f, 0.f};

    int jt0 = j0 >> 4;
    int jti = i >> 4;

    for (int kk = 0; kk < 8; ++kk) {
        int kkm = kk & 3;
        bool isPr = kk >= 4;
        short8 bfr[8];
#pragma unroll
        for (int n = 0; n < 8; ++n)
            bfr[n] = *(const short8*)&lds[32768 + ((kk * 8 + n) * 64 + lane) * 8];
        short8 hi8 = *(const short8*)&lds[jti * 2048 + kkm * 512 + g * 128 + (i & 15) * 8];
        float hif[8];
#pragma unroll
        for (int e = 0; e < 8; ++e) hif[e] = bf2f((unsigned short)hi8[e]);
#pragma unroll
        for (int m = 0; m < 4; ++m) {
            short8 hj8 = *(const short8*)&lds[(jt0 + m) * 2048 + kkm * 512 + lane * 8];
            short8 a;
#pragma unroll
            for (int e = 0; e < 8; ++e) {
                float hj = bf2f((unsigned short)hj8[e]);
                float v = isPr ? hif[e] * hj : fabsf(hif[e] - hj);
                // truncating bf16 pack: 1 op vs 3-op RTNE (error <= 1 ulp bf16)
                a[e] = (short)(__builtin_bit_cast(unsigned int, v) >> 16);
            }
#pragma unroll
            for (int n = 0; n < 8; ++n)
                acc[m][n] = __builtin_amdgcn_mfma_f32_16x16x32_bf16(a, bfr[n], acc[m][n], 0, 0, 0);
        }
    }
    {   // kk = 8: ev features straight from ev_bf (already bf16, padded to 32)
        short8 bfr[8];
#pragma unroll
        for (int n = 0; n < 8; ++n)
            bfr[n] = *(const short8*)&lds[32768 + ((64 + n) * 64 + lane) * 8];
#pragma unroll
        for (int m = 0; m < 4; ++m) {
            int j = j0 + 16 * m + l15;
            short8 a = *(const short8*)&ev_bf[((size_t)(bi * 256 + j)) * 32 + 8 * g];
#pragma unroll
            for (int n = 0; n < 8; ++n)
                acc[m][n] = __builtin_amdgcn_mfma_f32_16x16x32_bf16(a, bfr[n], acc[m][n], 0, 0, 0);
        }
    }
    // epilogue: + Ti[k] + Tj[j][k], relu, * w1[k], reduce over k, write e_pre
#pragma unroll
    for (int m = 0; m < 4; ++m) {
        int jb = j0 + 16 * m + 4 * g;
        float s0 = 0.f, s1 = 0.f, s2 = 0.f, s3 = 0.f;
#pragma unroll
        for (int n = 0; n < 8; ++n) {
            int kidx = 16 * n + l15;
            uint2 tj = *(const uint2*)&Tjt[((size_t)(b * 128 + kidx)) * 256 + jb];
            float tb = ti[n];
            float h0 = acc[m][n][0] + tb + bf2f((unsigned short)(tj.x & 0xffff));
            float h1 = acc[m][n][1] + tb + bf2f((unsigned short)(tj.x >> 16));
            float h2 = acc[m][n][2] + tb + bf2f((unsigned short)(tj.y & 0xffff));
            float h3 = acc[m][n][3] + tb + bf2f((unsigned short)(tj.y >> 16));
            float wk = w1r[n];
            s0 += fmaxf(h0, 0.f) * wk;
            s1 += fmaxf(h1, 0.f) * wk;
            s2 += fmaxf(h2, 0.f) * wk;
            s3 += fmaxf(h3, 0.f) * wk;
        }
#pragma unroll
        for (int mk = 1; mk < 16; mk <<= 1) {
            s0 += __shfl_xor(s0, mk);
            s1 += __shfl_xor(s1, mk);
            s2 += __shfl_xor(s2, mk);
            s3 += __shfl_xor(s3, mk);
        }
        if (l15 == 0)
            *(float4*)&ep[(size_t)bi * 256 + jb] = make_float4(s0, s1, s2, s3);
    }
}

// ---------- final e: pure BW — ep/hint + transposed tiles ----------
__global__ __launch_bounds__(256) void k_final(const float* __restrict__ ep,
        const float* __restrict__ hint, const float* __restrict__ eh1b,
        float* __restrict__ e_out) {
    int blk = blockIdx.x;
    int b = blk >> 6;
    int ti = (blk >> 3) & 7, tj = blk & 7;
    int i0 = ti * 32, j0 = tj * 32;
    int t = threadIdx.x;
    int c = t & 31;
    int r4 = (t >> 5) * 4;
    __shared__ float epT[32][33], hT[32][33];
#pragma unroll
    for (int q = 0; q < 4; ++q) {
        int r = r4 + q;
        int src = ((b << 8) + j0 + r) * 256 + i0 + c;
        epT[c][r] = ep[src];
        hT[c][r] = hint[src];
    }
    __syncthreads();
    float bias2 = 2.0f * eh1b[0];
#pragma unroll
    for (int q = 0; q < 4; ++q) {
        int a = r4 + q;
        int i = i0 + a, j = j0 + c;
        int idx = ((b << 8) + i) * 256 + j;
        float s = ep[idx] + hint[idx] + epT[a][c] + hT[a][c] + bias2;
        e_out[idx] = (i == j) ? NEG_INF : 0.5f * s;
    }
}

extern "C" void kernel_launch(void* const* d_in, const int* in_sizes, int n_in,
                              void* d_out, int out_size, void* d_ws, size_t ws_size,
                              hipStream_t stream) {
    const float* slots = (const float*)d_in[0];
    const float* rel   = (const float*)d_in[1];
    const float* sup   = (const float*)d_in[2];
    const float* wit   = (const float*)d_in[3];
    const float* bun   = (const float*)d_in[4];
    const float* ve_in_w = (const float*)d_in[5];
    const float* ve_in_b = (const float*)d_in[6];
    const float* ve_w[3] = {(const float*)d_in[7], (const float*)d_in[9], (const float*)d_in[11]};
    const float* ve_b[3] = {(const float*)d_in[8], (const float*)d_in[10], (const float*)d_in[12]};
    const float* nf0w = (const float*)d_in[13];
    const float* nf0b = (const float*)d_in[14];
    const float* nf1w = (const float*)d_in[15];
    const float* nf1b = (const float*)d_in[16];
    const float* th0w = (const float*)d_in[17];
    const float* th0b = (const float*)d_in[18];
    const float* th1w = (const float*)d_in[19];
    const float* th1b = (const float*)d_in[20];
    const float* sh0w = (const float*)d_in[21];
    const float* sh0b = (const float*)d_in[22];
    const float* sh1w = (const float*)d_in[23];
    const float* sh1b = (const float*)d_in[24];
    const float* eh0w = (const float*)d_in[25];
    const float* eh0b = (const float*)d_in[26];
    const float* eh1w = (const float*)d_in[27];
    const float* eh1b = (const float*)d_in[28];

    float* out = (float*)d_out;
    float* o_node = out;
    float* o_vl   = out + 131072;
    float* o_tl   = out + 524288;
    float* o_sp   = out + 527360;
    float* o_e    = out + 531456;
    float* o_rm   = out + 793600;
    float* o_rs   = out + 1055744;
    float* o_sm   = out + 1317888;
    float* o_ss   = out + 1580032;
    float* o_wm   = out + 1842176;
    float* o_wsd  = out + 2104320;

    float* ws  = (float*)d_ws;
    float* h_a = ws;                                   // 393216
    float* h_b = ws + 393216;                          // 393216
    float* Ti  = ws + 786432;                          // 131072
    float* ep  = ws + 917504;                          // 262144
    unsigned short* ev_bf  = (unsigned short*)(ws + 1179648);  // 8388608 hw
    unsigned short* Tjt    = (unsigned short*)(ws + 5373952);  // 131072 hw
    unsigned short* nodeSg = (unsigned short*)(ws + 5439488);  // 131072 hw
    unsigned short* Bs_g   = (unsigned short*)(ws + 5505024);  // 36864 hw
    float* hint = ws + 5523456;                        // 262144 (ends 5785600 = 23.1 MB)

    k_in_proj<<<768, 128, 0, stream>>>(slots, ve_in_w, ve_in_b, h_a);
    // MP layer 0 merged with independent stats/hint/prep work (fills idle CUs)
    k_mp_stats<<<1936, 256, 0, stream>>>(rel, h_a, ve_w[0], ve_b[0], h_b,
                                         rel, sup, wit, bun, ev_bf,
                                         o_rm, o_rs, o_sm, o_ss, o_wm, o_wsd,
                                         eh0w, Bs_g, hint);
    k_mp<<<768, 256, 0, stream>>>(rel, h_b, ve_w[1], ve_b[1], h_a);
    k_mp<<<768, 256, 0, stream>>>(rel, h_a, ve_w[2], ve_b[2], o_vl);

    k_fuse<<<512, 256, 0, stream>>>(o_vl, nf0w, nf0b, nf1w, nf1b,
                                    th0w, th0b, th1w, th1b,
                                    sh0w, sh0b, sh1w, sh1b,
                                    eh0w, eh0b,
                                    o_node, nodeSg, o_tl, o_sp, Ti, Tjt);
    k_edge<<<512, 512, 0, stream>>>(nodeSg, Bs_g, ev_bf, Tjt, Ti, eh1w, ep);
    k_final<<<256, 256, 0, stream>>>(ep, hint, eh1b, o_e);
}